// Round 4
// baseline (202.000 us; speedup 1.0000x reference)
//
#include <hip/hip_runtime.h>
#include <stdint.h>

// SimCLR loss, B=4096, D=512, TAU=0.1.  out[0]=loss, out[1]=acc(%).
//
// Round 4: round-3 topology (32 rows/wave, shared staged fragment feeds both
// a-left and b-left MFMAs = best LDS economy) made register-feasible via fp8
// e4m3: full-K both-view left fragments = 128 VGPRs (bf16 needed 256 -> spill,
// the round-3 killer). 2 blocks/CU, 2 waves/SIMD, 32KB fp8 tiles double-
// buffered. MFMA-bound by design: LDS ~10us vs MFMA ~27.5us floor.
// Label logit kept exact in fp32 (computed in prep), diagonals masked in-
// kernel, so fp8 noise only perturbs the non-label logsumexp terms.

#define BN 4096
#define DK 512            // K elements = bytes per row in fp8
#define NSPLIT 16
#define NEG_BIG -1e30f
#define SCL 0.15625f      // 1/(8*8*TAU): undo fp8 pre-scale s=8, apply 1/tau
#define TILE_BYTES (64 * DK)  // 32 KB per 64-col fp8 tile

typedef __attribute__((ext_vector_type(16))) float floatx16;

__device__ __forceinline__ void mlmerge(float& m, float& l, float m2, float l2) {
  float mn = fmaxf(m, m2);
  l = l * __expf(m - mn) + l2 * __expf(m2 - mn);
  m = mn;
}

// ---------------- prep: normalize, fp8-pack (K-permuted), label logits ----
// Permuted layout: byte position kc2*32 + h*16 + t*8 + j  holds original
// k = kc2*32 + t*16 + h*8 + j.  One 16B chunk (kc2,h) = the h-half-wave's
// A/B-fragment bytes for BOTH kc=2*kc2 and kc=2*kc2+1 (32x32x16 layout:
// lane holds elems k = kc*16 + (lane>>5)*8 + j).
__global__ void __launch_bounds__(256) prep_kernel(
    const float* __restrict__ A, const float* __restrict__ Bv,
    unsigned char* __restrict__ An, unsigned char* __restrict__ Bn,
    float* __restrict__ diag, float* __restrict__ out) {
  if (blockIdx.x == 0 && threadIdx.x < 2) out[threadIdx.x] = 0.0f;
  const int w = threadIdx.x >> 6, lane = threadIdx.x & 63;
  const int row = blockIdx.x * 4 + w;
  const float4* pa4 = (const float4*)(A + (size_t)row * DK);
  const float4* pb4 = (const float4*)(Bv + (size_t)row * DK);
  float4 a0 = pa4[lane * 2], a1 = pa4[lane * 2 + 1];  // k = lane*8 .. +7
  float4 b0 = pb4[lane * 2], b1 = pb4[lane * 2 + 1];
  float ssa = a0.x * a0.x + a0.y * a0.y + a0.z * a0.z + a0.w * a0.w +
              a1.x * a1.x + a1.y * a1.y + a1.z * a1.z + a1.w * a1.w;
  float ssb = b0.x * b0.x + b0.y * b0.y + b0.z * b0.z + b0.w * b0.w +
              b1.x * b1.x + b1.y * b1.y + b1.z * b1.z + b1.w * b1.w;
  float sab = a0.x * b0.x + a0.y * b0.y + a0.z * b0.z + a0.w * b0.w +
              a1.x * b1.x + a1.y * b1.y + a1.z * b1.z + a1.w * b1.w;
#pragma unroll
  for (int off = 32; off > 0; off >>= 1) {
    ssa += __shfl_xor(ssa, off);
    ssb += __shfl_xor(ssb, off);
    sab += __shfl_xor(sab, off);
  }
  float na = fmaxf(sqrtf(ssa), 1e-12f);
  float nb = fmaxf(sqrtf(ssb), 1e-12f);
  const float s = 8.0f;  // fp8 pre-scale: elems ~N(0,1/sqrt(512))*8 mid-range
  float sa = s / na, sb = s / nb;
  // permuted destination byte offset for this lane's 8 contiguous k
  const int doff = (lane >> 2) * 32 + (lane & 1) * 16 + ((lane >> 1) & 1) * 8;
  {
    int v0 = __builtin_amdgcn_cvt_pk_fp8_f32(a0.x * sa, a0.y * sa, 0, false);
    v0 = __builtin_amdgcn_cvt_pk_fp8_f32(a0.z * sa, a0.w * sa, v0, true);
    int v1 = __builtin_amdgcn_cvt_pk_fp8_f32(a1.x * sa, a1.y * sa, 0, false);
    v1 = __builtin_amdgcn_cvt_pk_fp8_f32(a1.z * sa, a1.w * sa, v1, true);
    int2 pv; pv.x = v0; pv.y = v1;
    *(int2*)(An + (size_t)row * DK + doff) = pv;
  }
  {
    int v0 = __builtin_amdgcn_cvt_pk_fp8_f32(b0.x * sb, b0.y * sb, 0, false);
    v0 = __builtin_amdgcn_cvt_pk_fp8_f32(b0.z * sb, b0.w * sb, v0, true);
    int v1 = __builtin_amdgcn_cvt_pk_fp8_f32(b1.x * sb, b1.y * sb, 0, false);
    v1 = __builtin_amdgcn_cvt_pk_fp8_f32(b1.z * sb, b1.w * sb, v1, true);
    int2 pv; pv.x = v0; pv.y = v1;
    *(int2*)(Bn + (size_t)row * DK + doff) = pv;
  }
  if (lane == 0) diag[row] = (sab / (na * nb)) * 10.0f;  // exact fp32 /TAU
}

// ---------------- tiles: fp8 MFMA, 128-row blocks, dbuf LDS ---------------
// grid = (32 row-blocks, 16 col-splits) = 512 blocks = 2/CU. 4 waves/block,
// wave owns 32 rows, both views' full-K fragments resident (128 VGPRs).
__global__ void __launch_bounds__(256, 2) tiles_kernel(
    const unsigned char* __restrict__ An, const unsigned char* __restrict__ Bn,
    float* __restrict__ pmA, float* __restrict__ plA,
    float* __restrict__ pmB, float* __restrict__ plB) {
  __shared__ __align__(16) unsigned char smem[2 * TILE_BYTES];  // 64 KB

  const int rb = blockIdx.x;     // 0..31 (128-row panel)
  const int split = blockIdx.y;  // 0..15 (8 j-tiles each)
  const int tid = threadIdx.x;
  const int lane = tid & 63, w = tid >> 6;
  const int n5 = lane & 31, h = lane >> 5;
  const int r0 = rb * 128;

  // persistent left fragments (permuted layout -> one long2 = 2 kc frags)
  long afA[32], afB[32];
  {
    const int myrow = r0 + w * 32 + n5;
    const unsigned char* pa = An + (size_t)myrow * DK + h * 16;
    const unsigned char* pb = Bn + (size_t)myrow * DK + h * 16;
#pragma unroll
    for (int kc2 = 0; kc2 < 16; ++kc2) {
      long2 va = *(const long2*)(pa + kc2 * 32);
      afA[2 * kc2] = va.x; afA[2 * kc2 + 1] = va.y;
      long2 vb = *(const long2*)(pb + kc2 * 32);
      afB[2 * kc2] = vb.x; afB[2 * kc2 + 1] = vb.y;
    }
  }

  // online softmax state: C/D row = (r&3) + 8*(r>>2) + 4*h, col = cs*32+n5
  float mA[16], lA[16], mB[16], lB[16];
#pragma unroll
  for (int r = 0; r < 16; ++r) { mA[r] = NEG_BIG; lA[r] = 0.f; mB[r] = NEG_BIG; lB[r] = 0.f; }

  // stage a 64-col fp8 tile; one inst = 2 cols (lanes 0-31 col even, 32-63
  // odd). XOR swizzle: physical 16B chunk p of col c holds logical p^(c&7).
  auto stage = [&](unsigned char* buf, int jt) {
    const unsigned char* csrc = (jt < 64) ? An : Bn;
    const int cb = (jt & 63) * 64;
#pragma unroll
    for (int ii = 0; ii < 8; ++ii) {  // wave w: colpairs w*8 .. w*8+7
      const int cp = w * 8 + ii;
      const int cl = cp * 2 + h;  // col within tile (per-lane)
      const unsigned char* src =
          csrc + (size_t)(cb + cl) * DK + ((n5 ^ (cl & 7)) * 16);
      __builtin_amdgcn_global_load_lds(
          (const __attribute__((address_space(1))) void*)src,
          (__attribute__((address_space(3))) void*)(buf + cp * 1024),
          16, 0, 0);
    }
  };

  stage(smem, split * 8);
  __syncthreads();

  for (int t = 0; t < 8; ++t) {
    const int jt = split * 8 + t;
    unsigned char* cur = smem + (t & 1) * TILE_BYTES;
    unsigned char* nxt = smem + ((t + 1) & 1) * TILE_BYTES;
    if (t < 7) stage(nxt, jt + 1);  // prefetch; drained at this iter's barrier

    floatx16 accA[2], accB[2];
#pragma unroll
    for (int cs = 0; cs < 2; ++cs)
#pragma unroll
      for (int r = 0; r < 16; ++r) { accA[cs][r] = 0.f; accB[cs][r] = 0.f; }

    // B-frag: col cs*32+n5, logical chunk 2*kc2+h -> long2 = frags for
    // kc=2*kc2 (.x) and kc=2*kc2+1 (.y)
    const unsigned char* bbase = cur + (size_t)n5 * DK;
#pragma unroll
    for (int kc2 = 0; kc2 < 16; ++kc2) {
      const int chunk = ((2 * kc2 + h) ^ (n5 & 7)) * 16;
#pragma unroll
      for (int cs = 0; cs < 2; ++cs) {
        long2 bv = *(const long2*)(bbase + cs * 32 * DK + chunk);
        accA[cs] = __builtin_amdgcn_mfma_f32_32x32x16_fp8_fp8(afA[2 * kc2], bv.x, accA[cs], 0, 0, 0);
        accB[cs] = __builtin_amdgcn_mfma_f32_32x32x16_fp8_fp8(afB[2 * kc2], bv.x, accB[cs], 0, 0, 0);
        accA[cs] = __builtin_amdgcn_mfma_f32_32x32x16_fp8_fp8(afA[2 * kc2 + 1], bv.y, accA[cs], 0, 0, 0);
        accB[cs] = __builtin_amdgcn_mfma_f32_32x32x16_fp8_fp8(afB[2 * kc2 + 1], bv.y, accB[cs], 0, 0, 0);
      }
    }

    // scale to logits, mask (i,i) of this half (aa/bb diag AND ab label —
    // label re-added exactly in finalize), online update
    const bool dtile = (((jt & 63) >> 1) == rb);
    const int colbase = (jt & 63) * 64;
#pragma unroll
    for (int r = 0; r < 16; ++r) {
      const int rowg = r0 + w * 32 + (r & 3) + 8 * (r >> 2) + 4 * h;
      float va0 = accA[0][r] * SCL, va1 = accA[1][r] * SCL;
      float vb0 = accB[0][r] * SCL, vb1 = accB[1][r] * SCL;
      if (dtile) {
        if (rowg == colbase + n5)      { va0 = NEG_BIG; vb0 = NEG_BIG; }
        if (rowg == colbase + 32 + n5) { va1 = NEG_BIG; vb1 = NEG_BIG; }
      }
      {
        float mn = fmaxf(mA[r], fmaxf(va0, va1));
        lA[r] = lA[r] * __expf(mA[r] - mn) + __expf(va0 - mn) + __expf(va1 - mn);
        mA[r] = mn;
      }
      {
        float mn = fmaxf(mB[r], fmaxf(vb0, vb1));
        lB[r] = lB[r] * __expf(mB[r] - mn) + __expf(vb0 - mn) + __expf(vb1 - mn);
        mB[r] = mn;
      }
    }
    __syncthreads();  // cur consumed; nxt's DMA drained
  }

  // merge across the 32 n5-lanes (cols); h-groups hold different rows
#pragma unroll
  for (int off = 1; off < 32; off <<= 1) {
#pragma unroll
    for (int r = 0; r < 16; ++r) {
      float mo = __shfl_xor(mA[r], off), lo = __shfl_xor(lA[r], off);
      mlmerge(mA[r], lA[r], mo, lo);
      mo = __shfl_xor(mB[r], off); lo = __shfl_xor(lB[r], off);
      mlmerge(mB[r], lB[r], mo, lo);
    }
  }
  if (n5 == 0) {
    const int base = split * BN;
#pragma unroll
    for (int r = 0; r < 16; ++r) {
      const int row = r0 + w * 32 + (r & 3) + 8 * (r >> 2) + 4 * h;
      pmA[base + row] = mA[r];
      plA[base + row] = lA[r];
      pmB[base + row] = mB[r];
      plB[base + row] = lB[r];
    }
  }
}

// ---------------- finalize: merge 16 splits, add label, reduce ------------
__global__ void __launch_bounds__(256) finalize_kernel(
    const float* __restrict__ pmA, const float* __restrict__ plA,
    const float* __restrict__ pmB, const float* __restrict__ plB,
    const float* __restrict__ diag, float* __restrict__ out) {
  const int row = blockIdx.x * 256 + threadIdx.x;
  float Ma = NEG_BIG, La = 0.f, Mb = NEG_BIG, Lb = 0.f;
#pragma unroll
  for (int s = 0; s < NSPLIT; ++s) {
    mlmerge(Ma, La, pmA[s * BN + row], plA[s * BN + row]);
    mlmerge(Mb, Lb, pmB[s * BN + row], plB[s * BN + row]);
  }
  const float d = diag[row];
  float corr = (d >= Ma) ? 1.f : 0.f;  // argmax(full_a)==label
  float mna = fmaxf(Ma, d);
  float lseA = mna + logf(La * __expf(Ma - mna) + __expf(d - mna));
  float mnb = fmaxf(Mb, d);
  float lseB = mnb + logf(Lb * __expf(Mb - mnb) + __expf(d - mnb));
  float lossi = (lseA - d) + (lseB - d);
#pragma unroll
  for (int off = 32; off > 0; off >>= 1) {
    lossi += __shfl_xor(lossi, off);
    corr += __shfl_xor(corr, off);
  }
  __shared__ float sred[2][4];
  if ((threadIdx.x & 63) == 0) {
    int w = threadIdx.x >> 6;
    sred[0][w] = lossi; sred[1][w] = corr;
  }
  __syncthreads();
  if (threadIdx.x == 0) {
    float ls = sred[0][0] + sred[0][1] + sred[0][2] + sred[0][3];
    float cs = sred[1][0] + sred[1][1] + sred[1][2] + sred[1][3];
    atomicAdd(&out[0], ls * (1.0f / 8192.0f));    // mean over rows, /2
    atomicAdd(&out[1], cs * (100.0f / 4096.0f));  // accuracy %
  }
}

extern "C" void kernel_launch(void* const* d_in, const int* in_sizes, int n_in,
                              void* d_out, int out_size, void* d_ws, size_t ws_size,
                              hipStream_t stream) {
  const float* A = (const float*)d_in[0];
  const float* Bv = (const float*)d_in[1];
  unsigned char* An = (unsigned char*)d_ws;                   // 4096x512 fp8
  unsigned char* Bn = An + (size_t)BN * DK;                   // 4096x512 fp8
  float* diag = (float*)(Bn + (size_t)BN * DK);               // 4096 f32
  float* pmA = diag + BN;                                     // [16][4096] each
  float* plA = pmA + NSPLIT * BN;
  float* pmB = plA + NSPLIT * BN;
  float* plB = pmB + NSPLIT * BN;
  float* out = (float*)d_out;

  prep_kernel<<<BN / 4, 256, 0, stream>>>(A, Bv, An, Bn, diag, out);
  tiles_kernel<<<dim3(32, 16), 256, 0, stream>>>(An, Bn, pmA, plA, pmB, plB);
  finalize_kernel<<<BN / 256, 256, 0, stream>>>(pmA, plA, pmB, plB, diag, out);
}

// Round 5
// 135.433 us; speedup vs baseline: 1.4915x; 1.4915x over previous
//
#include <hip/hip_runtime.h>
#include <stdint.h>

// SimCLR loss, B=4096, D=512, TAU=0.1.  out[0]=loss, out[1]=acc(%).
//
// Round 5: fp8 e4m3 32x32x16 MFMA, TWO-PASS per block (view a, then view b).
// Round 4's both-views-resident scheme needed ~280 regs -> spilled 900 B/thr
// to scratch (WRITE_SIZE 118 MB, the round-4 killer). One view resident =
// 64 VGPR frags; live set ~155 regs -> fits 2 waves/SIMD with margin.
// LDS reads per MFMA double vs round 4 but stay under MFMA: per CU-tile-iter
// LDS ~3000 cyc vs MFMA ~4130 cyc. Tiles restaged once per pass from the
// 4 MB L2-resident fp8 dataset. Label logit exact fp32 (prep), diagonals
// masked in-kernel, re-added in finalize.

#define BN 4096
#define DK 512            // K elements = bytes per row in fp8
#define NSPLIT 16
#define NEG_BIG -1e30f
#define SCL 0.15625f      // 1/(8*8*TAU): undo fp8 pre-scale s=8, apply 1/tau
#define TILE_BYTES (64 * DK)  // 32 KB per 64-col fp8 tile

typedef __attribute__((ext_vector_type(16))) float floatx16;

__device__ __forceinline__ void mlmerge(float& m, float& l, float m2, float l2) {
  float mn = fmaxf(m, m2);
  l = l * __expf(m - mn) + l2 * __expf(m2 - mn);
  m = mn;
}

// ---------------- prep: normalize, fp8-pack (K-permuted), label logits ----
// Permuted layout: byte position kc2*32 + h*16 + t*8 + j holds original
// k = kc2*32 + t*16 + h*8 + j.  One 16B chunk (kc2,h) = the h-half-wave's
// fragment bytes for kc=2*kc2 and kc=2*kc2+1 (32x32x16 A/B layout:
// lane holds elems k = kc*16 + (lane>>5)*8 + j).
__global__ void __launch_bounds__(256) prep_kernel(
    const float* __restrict__ A, const float* __restrict__ Bv,
    unsigned char* __restrict__ An, unsigned char* __restrict__ Bn,
    float* __restrict__ diag, float* __restrict__ out) {
  if (blockIdx.x == 0 && threadIdx.x < 2) out[threadIdx.x] = 0.0f;
  const int w = threadIdx.x >> 6, lane = threadIdx.x & 63;
  const int row = blockIdx.x * 4 + w;
  const float4* pa4 = (const float4*)(A + (size_t)row * DK);
  const float4* pb4 = (const float4*)(Bv + (size_t)row * DK);
  float4 a0 = pa4[lane * 2], a1 = pa4[lane * 2 + 1];  // k = lane*8 .. +7
  float4 b0 = pb4[lane * 2], b1 = pb4[lane * 2 + 1];
  float ssa = a0.x * a0.x + a0.y * a0.y + a0.z * a0.z + a0.w * a0.w +
              a1.x * a1.x + a1.y * a1.y + a1.z * a1.z + a1.w * a1.w;
  float ssb = b0.x * b0.x + b0.y * b0.y + b0.z * b0.z + b0.w * b0.w +
              b1.x * b1.x + b1.y * b1.y + b1.z * b1.z + b1.w * b1.w;
  float sab = a0.x * b0.x + a0.y * b0.y + a0.z * b0.z + a0.w * b0.w +
              a1.x * b1.x + a1.y * b1.y + a1.z * b1.z + a1.w * b1.w;
#pragma unroll
  for (int off = 32; off > 0; off >>= 1) {
    ssa += __shfl_xor(ssa, off);
    ssb += __shfl_xor(ssb, off);
    sab += __shfl_xor(sab, off);
  }
  float na = fmaxf(sqrtf(ssa), 1e-12f);
  float nb = fmaxf(sqrtf(ssb), 1e-12f);
  const float s = 8.0f;  // fp8 pre-scale: keeps elems mid-range in e4m3
  float sa = s / na, sb = s / nb;
  const int doff = (lane >> 2) * 32 + (lane & 1) * 16 + ((lane >> 1) & 1) * 8;
  {
    int v0 = __builtin_amdgcn_cvt_pk_fp8_f32(a0.x * sa, a0.y * sa, 0, false);
    v0 = __builtin_amdgcn_cvt_pk_fp8_f32(a0.z * sa, a0.w * sa, v0, true);
    int v1 = __builtin_amdgcn_cvt_pk_fp8_f32(a1.x * sa, a1.y * sa, 0, false);
    v1 = __builtin_amdgcn_cvt_pk_fp8_f32(a1.z * sa, a1.w * sa, v1, true);
    int2 pv; pv.x = v0; pv.y = v1;
    *(int2*)(An + (size_t)row * DK + doff) = pv;
  }
  {
    int v0 = __builtin_amdgcn_cvt_pk_fp8_f32(b0.x * sb, b0.y * sb, 0, false);
    v0 = __builtin_amdgcn_cvt_pk_fp8_f32(b0.z * sb, b0.w * sb, v0, true);
    int v1 = __builtin_amdgcn_cvt_pk_fp8_f32(b1.x * sb, b1.y * sb, 0, false);
    v1 = __builtin_amdgcn_cvt_pk_fp8_f32(b1.z * sb, b1.w * sb, v1, true);
    int2 pv; pv.x = v0; pv.y = v1;
    *(int2*)(Bn + (size_t)row * DK + doff) = pv;
  }
  if (lane == 0) diag[row] = (sab / (na * nb)) * 10.0f;  // exact fp32 /TAU
}

// ---------------- tiles: fp8 MFMA, 128-row blocks, 2 passes, dbuf LDS -----
// grid = (32 row-blocks, 16 col-splits) = 512 blocks = 2/CU. 4 waves/block,
// wave owns 32 rows. Pass 0: a-frags resident -> full_a stats over this
// split's 8 tiles. Pass 1: b-frags -> full_b, same tiles restaged (L2-hot).
__global__ void __launch_bounds__(256, 2) tiles_kernel(
    const unsigned char* __restrict__ An, const unsigned char* __restrict__ Bn,
    float* __restrict__ pmA, float* __restrict__ plA,
    float* __restrict__ pmB, float* __restrict__ plB) {
  __shared__ __align__(16) unsigned char smem[2 * TILE_BYTES];  // 64 KB

  const int rb = blockIdx.x;     // 0..31 (128-row panel)
  const int split = blockIdx.y;  // 0..15 (8 j-tiles each)
  const int tid = threadIdx.x;
  const int lane = tid & 63, w = tid >> 6;
  const int n5 = lane & 31, h = lane >> 5;
  const int r0 = rb * 128;
  const int myrow = r0 + w * 32 + n5;

  // one view's left fragments (permuted layout -> one long2 = 2 kc frags)
  long af[32];
  auto loadfrags = [&](const unsigned char* base) {
    const unsigned char* p = base + (size_t)myrow * DK + h * 16;
#pragma unroll
    for (int kc2 = 0; kc2 < 16; ++kc2) {
      long2 v = *(const long2*)(p + kc2 * 32);
      af[2 * kc2] = v.x; af[2 * kc2 + 1] = v.y;
    }
  };

  // online softmax state: C/D row = (r&3) + 8*(r>>2) + 4*h, col = cs*32+n5
  float m[16], l[16];
#pragma unroll
  for (int r = 0; r < 16; ++r) { m[r] = NEG_BIG; l[r] = 0.f; }

  // merge across n5 lanes (cols), write stats for this pass, reset state
  auto flush = [&](float* pm, float* pl) {
#pragma unroll
    for (int off = 1; off < 32; off <<= 1)
#pragma unroll
      for (int r = 0; r < 16; ++r) {
        float mo = __shfl_xor(m[r], off), lo = __shfl_xor(l[r], off);
        mlmerge(m[r], l[r], mo, lo);
      }
    if (n5 == 0) {
      const int base = split * BN;
#pragma unroll
      for (int r = 0; r < 16; ++r) {
        const int row = r0 + w * 32 + (r & 3) + 8 * (r >> 2) + 4 * h;
        pm[base + row] = m[r];
        pl[base + row] = l[r];
      }
    }
#pragma unroll
    for (int r = 0; r < 16; ++r) { m[r] = NEG_BIG; l[r] = 0.f; }
  };

  // stage a 64-col fp8 tile; one inst = 2 cols (h=0 even col, h=1 odd).
  // XOR swizzle: physical 16B chunk p of col c holds logical chunk p^(c&7).
  auto stage = [&](unsigned char* buf, int jt) {
    const unsigned char* csrc = (jt < 64) ? An : Bn;
    const int cb = (jt & 63) * 64;
#pragma unroll
    for (int ii = 0; ii < 8; ++ii) {  // wave w: colpairs w*8 .. w*8+7
      const int cp = w * 8 + ii;
      const int cl = cp * 2 + h;
      const unsigned char* src =
          csrc + (size_t)(cb + cl) * DK + ((n5 ^ (cl & 7)) * 16);
      __builtin_amdgcn_global_load_lds(
          (const __attribute__((address_space(1))) void*)src,
          (__attribute__((address_space(3))) void*)(buf + cp * 1024),
          16, 0, 0);
    }
  };

  stage(smem, split * 8);
  loadfrags(An);
  __syncthreads();

  for (int u = 0; u < 16; ++u) {
    const int t = u & 7;
    const int jt = split * 8 + t;
    unsigned char* cur = smem + (u & 1) * TILE_BYTES;
    unsigned char* nxt = smem + ((u + 1) & 1) * TILE_BYTES;
    if (u < 15) stage(nxt, split * 8 + ((t + 1) & 7));  // prefetch
    if (u == 8) {         // pass boundary: emit full_a, switch to b-frags
      flush(pmA, plA);
      loadfrags(Bn);
    }

    floatx16 acc[2];
#pragma unroll
    for (int cs = 0; cs < 2; ++cs)
#pragma unroll
      for (int r = 0; r < 16; ++r) acc[cs][r] = 0.f;

    // B-frag: col cs*32+n5, logical chunk 2*kc2+h -> long2 = frags for
    // kc=2*kc2 (.x) and kc=2*kc2+1 (.y)
    const unsigned char* bbase = cur + (size_t)n5 * DK;
#pragma unroll
    for (int kc2 = 0; kc2 < 16; ++kc2) {
      const int chunk = ((2 * kc2 + h) ^ (n5 & 7)) * 16;
#pragma unroll
      for (int cs = 0; cs < 2; ++cs) {
        long2 bv = *(const long2*)(bbase + cs * 32 * DK + chunk);
        acc[cs] = __builtin_amdgcn_mfma_f32_32x32x16_fp8_fp8(af[2 * kc2], bv.x, acc[cs], 0, 0, 0);
        acc[cs] = __builtin_amdgcn_mfma_f32_32x32x16_fp8_fp8(af[2 * kc2 + 1], bv.y, acc[cs], 0, 0, 0);
      }
    }

    // scale to logits, mask (i,i) of this half (aa/bb masked diag AND ab
    // label — label re-added exactly in finalize), online update
    const bool dtile = (((jt & 63) >> 1) == rb);
    const int colbase = (jt & 63) * 64;
#pragma unroll
    for (int r = 0; r < 16; ++r) {
      const int rowg = r0 + w * 32 + (r & 3) + 8 * (r >> 2) + 4 * h;
      float v0 = acc[0][r] * SCL, v1 = acc[1][r] * SCL;
      if (dtile) {
        if (rowg == colbase + n5)      v0 = NEG_BIG;
        if (rowg == colbase + 32 + n5) v1 = NEG_BIG;
      }
      float mn = fmaxf(m[r], fmaxf(v0, v1));
      l[r] = l[r] * __expf(m[r] - mn) + __expf(v0 - mn) + __expf(v1 - mn);
      m[r] = mn;
    }
    __syncthreads();  // cur consumed; nxt's DMA drained
  }

  flush(pmB, plB);
}

// ---------------- finalize: merge 16 splits, add label, reduce ------------
__global__ void __launch_bounds__(256) finalize_kernel(
    const float* __restrict__ pmA, const float* __restrict__ plA,
    const float* __restrict__ pmB, const float* __restrict__ plB,
    const float* __restrict__ diag, float* __restrict__ out) {
  const int row = blockIdx.x * 256 + threadIdx.x;
  float Ma = NEG_BIG, La = 0.f, Mb = NEG_BIG, Lb = 0.f;
#pragma unroll
  for (int s = 0; s < NSPLIT; ++s) {
    mlmerge(Ma, La, pmA[s * BN + row], plA[s * BN + row]);
    mlmerge(Mb, Lb, pmB[s * BN + row], plB[s * BN + row]);
  }
  const float d = diag[row];
  float corr = (d >= Ma) ? 1.f : 0.f;  // argmax(full_a)==label
  float mna = fmaxf(Ma, d);
  float lseA = mna + logf(La * __expf(Ma - mna) + __expf(d - mna));
  float mnb = fmaxf(Mb, d);
  float lseB = mnb + logf(Lb * __expf(Mb - mnb) + __expf(d - mnb));
  float lossi = (lseA - d) + (lseB - d);
#pragma unroll
  for (int off = 32; off > 0; off >>= 1) {
    lossi += __shfl_xor(lossi, off);
    corr += __shfl_xor(corr, off);
  }
  __shared__ float sred[2][4];
  if ((threadIdx.x & 63) == 0) {
    int w = threadIdx.x >> 6;
    sred[0][w] = lossi; sred[1][w] = corr;
  }
  __syncthreads();
  if (threadIdx.x == 0) {
    float ls = sred[0][0] + sred[0][1] + sred[0][2] + sred[0][3];
    float cs = sred[1][0] + sred[1][1] + sred[1][2] + sred[1][3];
    atomicAdd(&out[0], ls * (1.0f / 8192.0f));    // mean over rows, /2
    atomicAdd(&out[1], cs * (100.0f / 4096.0f));  // accuracy %
  }
}

extern "C" void kernel_launch(void* const* d_in, const int* in_sizes, int n_in,
                              void* d_out, int out_size, void* d_ws, size_t ws_size,
                              hipStream_t stream) {
  const float* A = (const float*)d_in[0];
  const float* Bv = (const float*)d_in[1];
  unsigned char* An = (unsigned char*)d_ws;                   // 4096x512 fp8
  unsigned char* Bn = An + (size_t)BN * DK;                   // 4096x512 fp8
  float* diag = (float*)(Bn + (size_t)BN * DK);               // 4096 f32
  float* pmA = diag + BN;                                     // [16][4096] each
  float* plA = pmA + NSPLIT * BN;
  float* pmB = plA + NSPLIT * BN;
  float* plB = pmB + NSPLIT * BN;
  float* out = (float*)d_out;

  prep_kernel<<<BN / 4, 256, 0, stream>>>(A, Bv, An, Bn, diag, out);
  tiles_kernel<<<dim3(32, 16), 256, 0, stream>>>(An, Bn, pmA, plA, pmB, plB);
  finalize_kernel<<<BN / 256, 256, 0, stream>>>(pmA, plA, pmB, plB, diag, out);
}